// Round 2
// baseline (888.510 us; speedup 1.0000x reference)
//
#include <hip/hip_runtime.h>
#include <hip/hip_fp16.h>

#define LEAKY 0.01f
#define BN_EPS 1e-5f

// ---------------- degree count ----------------
__global__ __launch_bounds__(256) void k_count(const int* __restrict__ dst,
                                               int* __restrict__ cnt, int e) {
  int i = blockIdx.x * 256 + threadIdx.x;
  if (i < e) atomicAdd(&cnt[dst[i]], 1);
}

// ---------------- exclusive scan A (fused dinv) ----------------
__global__ __launch_bounds__(256) void k_scanA(const int* __restrict__ in,
                                               int* __restrict__ out,
                                               int* __restrict__ bsums,
                                               float* __restrict__ dinv, int n) {
  __shared__ int sdata[256];
  int t = threadIdx.x;
  int base = blockIdx.x * 1024 + t * 4;
  int v[4];
#pragma unroll
  for (int j = 0; j < 4; j++) v[j] = (base + j < n) ? in[base + j] : 0;
#pragma unroll
  for (int j = 0; j < 4; j++)
    if (base + j < n) dinv[base + j] = rsqrtf((float)(v[j] + 1));  // +1 self-loop
  int tsum = v[0] + v[1] + v[2] + v[3];
  sdata[t] = tsum;
  __syncthreads();
  for (int off = 1; off < 256; off <<= 1) {
    int x = (t >= off) ? sdata[t - off] : 0;
    __syncthreads();
    sdata[t] += x;
    __syncthreads();
  }
  int run = sdata[t] - tsum;
#pragma unroll
  for (int j = 0; j < 4; j++) {
    if (base + j < n) out[base + j] = run;
    run += v[j];
  }
  if (t == 255) bsums[blockIdx.x] = sdata[255];
}

__global__ __launch_bounds__(256) void k_scanB(int* __restrict__ bsums, int nb) {
  __shared__ int sdata[256];
  int t = threadIdx.x;
  int v = (t < nb) ? bsums[t] : 0;
  sdata[t] = v;
  __syncthreads();
  for (int off = 1; off < 256; off <<= 1) {
    int x = (t >= off) ? sdata[t - off] : 0;
    __syncthreads();
    sdata[t] += x;
    __syncthreads();
  }
  if (t < nb) bsums[t] = sdata[t] - v;  // exclusive
}

// ---------------- CSR scatter (consumes counts down to 0; bsums fused) ----------------
__global__ __launch_bounds__(256) void k_scatter(const int* __restrict__ src,
                                                 const int* __restrict__ dst,
                                                 const int* __restrict__ off,
                                                 const int* __restrict__ bsums,
                                                 int* __restrict__ cnt,
                                                 int* __restrict__ csr, int e) {
  int i = blockIdx.x * 256 + threadIdx.x;
  if (i < e) {
    int d = dst[i];
    int p = off[d] + bsums[d >> 10] + (atomicSub(&cnt[d], 1) - 1);
    csr[p] = src[i];
  }
}

// ---------------- 64x64 GEMM: Y[n,64](fp16) = X[n,64](fp32) @ W ; BN+LeakyReLU fused on X
template <bool BN>
__global__ __launch_bounds__(256) void k_gemm(const float* __restrict__ X,
                                              const float* __restrict__ W,
                                              __half* __restrict__ Y, int n,
                                              const double* __restrict__ st,
                                              const float* __restrict__ gamma,
                                              const float* __restrict__ beta) {
  __shared__ float Ws[64][68];
  __shared__ float Xs[64][65];
  __shared__ float smu[64], sisd[64];
  int t = threadIdx.x;
  if (BN) {
    if (t < 64) {
      double mu = st[t] / n;
      double var = st[64 + t] / n - mu * mu;
      smu[t] = (float)mu;
      sisd[t] = (float)(1.0 / sqrt(var + (double)BN_EPS));
    }
    __syncthreads();
  }
  for (int j = t; j < 4096; j += 256) Ws[j >> 6][j & 63] = W[j];
  int rowbase = blockIdx.x * 64;
  for (int j = t; j < 4096; j += 256) {
    int r = j >> 6, c = j & 63;
    int gr = rowbase + r;
    float v = (gr < n) ? X[(size_t)gr * 64 + c] : 0.f;
    if (BN) {
      v = gamma[c] * (v - smu[c]) * sisd[c] + beta[c];
      v = (v >= 0.f) ? v : LEAKY * v;
    }
    Xs[r][c] = v;
  }
  __syncthreads();
  int r = t >> 2;
  int cq = t & 3;
  float acc[16];
#pragma unroll
  for (int j = 0; j < 16; j++) acc[j] = 0.f;
#pragma unroll 4
  for (int k = 0; k < 64; k++) {
    float xv = Xs[r][k];
#pragma unroll
    for (int j = 0; j < 16; j++) acc[j] += xv * Ws[k][cq * 16 + j];
  }
  int gr = rowbase + r;
  if (gr < n) {
    __half2* d2 = (__half2*)&Y[(size_t)gr * 64 + cq * 16];
#pragma unroll
    for (int q = 0; q < 8; q++)
      d2[q] = __halves2half2(__float2half(acc[2 * q]), __float2half(acc[2 * q + 1]));
  }
}

// ---------------- gather aggregation (8-deep ILP), optional fused BN stats ----------------
template <bool STATS>
__global__ __launch_bounds__(256) void k_agg(const __half* __restrict__ H,
                                             float* __restrict__ O,
                                             const int* __restrict__ off,
                                             const int* __restrict__ bsums,
                                             const int* __restrict__ csr,
                                             const float* __restrict__ dinv,
                                             const float* __restrict__ bias,
                                             double* __restrict__ st, int n, int e) {
  __shared__ double ls[4][64], lss[4][64];
  int wave = (blockIdx.x * 256 + threadIdx.x) >> 6;
  int lane = threadIdx.x & 63;
  int i = wave;
  float v = 0.f;
  if (i < n) {
    float di = dinv[i];
    int s0 = off[i] + bsums[i >> 10];
    int s1 = (i + 1 < n) ? (off[i + 1] + bsums[(i + 1) >> 10]) : e;
    float acc = __half2float(H[(size_t)i * 64 + lane]) * (di * di);
    for (int j = s0; j < s1; j += 8) {
      int idx[8];
      float w[8];
#pragma unroll
      for (int k = 0; k < 8; k++) idx[k] = (j + k < s1) ? csr[j + k] : i;
#pragma unroll
      for (int k = 0; k < 8; k++) w[k] = (j + k < s1) ? di * dinv[idx[k]] : 0.f;
      float hv[8];
#pragma unroll
      for (int k = 0; k < 8; k++) hv[k] = __half2float(H[(size_t)idx[k] * 64 + lane]);
#pragma unroll
      for (int k = 0; k < 8; k++) acc += hv[k] * w[k];
    }
    v = acc + bias[lane];
    O[(size_t)i * 64 + lane] = v;
  }
  if (STATS) {
    int w_ = threadIdx.x >> 6;
    ls[w_][lane] = (double)v;
    lss[w_][lane] = (double)v * (double)v;
    __syncthreads();
    if (w_ == 0) {
      double a = ls[0][lane] + ls[1][lane] + ls[2][lane] + ls[3][lane];
      double b = lss[0][lane] + lss[1][lane] + lss[2][lane] + lss[3][lane];
      atomicAdd(&st[lane], a);
      atomicAdd(&st[64 + lane], b);
    }
  }
}

extern "C" void kernel_launch(void* const* d_in, const int* in_sizes, int n_in,
                              void* d_out, int out_size, void* d_ws, size_t ws_size,
                              hipStream_t stream) {
  const float* x     = (const float*)d_in[0];
  const int*   ei    = (const int*)d_in[1];
  const float* W1    = (const float*)d_in[2];
  const float* b1    = (const float*)d_in[3];
  const float* gamma = (const float*)d_in[4];
  const float* beta  = (const float*)d_in[5];
  const float* W2    = (const float*)d_in[6];
  const float* b2    = (const float*)d_in[7];
  float* out = (float*)d_out;

  int n = in_sizes[0] / 64;
  int e = in_sizes[1] / 2;
  const int* srcv = ei;
  const int* dstv = ei + e;

  char* ws = (char*)d_ws;
  size_t p = 0;
  auto alloc = [&](size_t bytes) {
    void* r = ws + p;
    p += (bytes + 255) & ~(size_t)255;
    return r;
  };
  int*    counts = (int*)alloc((size_t)n * 4);
  int*    off    = (int*)alloc((size_t)n * 4);
  int*    bsums  = (int*)alloc(1024);
  float*  dinv   = (float*)alloc((size_t)n * 4);
  int*    csr    = (int*)alloc((size_t)e * 4);
  double* st     = (double*)alloc(128 * 8);
  __half* Ah     = (__half*)alloc((size_t)n * 64 * 2);  // gemm output (gathered), fp16
  float*  B      = (float*)alloc((size_t)n * 64 * 4);   // agg1 output, fp32

  hipMemsetAsync(counts, 0, (size_t)n * 4, stream);
  hipMemsetAsync(st, 0, 128 * 8, stream);

  int gE = (e + 255) / 256;
  int nb = (n + 1023) / 1024;
  int gG = (n + 63) / 64;
  int gAgg = (n + 3) / 4;

  k_count<<<gE, 256, 0, stream>>>(dstv, counts, e);
  k_scanA<<<nb, 256, 0, stream>>>(counts, off, bsums, dinv, n);
  k_scanB<<<1, 256, 0, stream>>>(bsums, nb);
  k_scatter<<<gE, 256, 0, stream>>>(srcv, dstv, off, bsums, counts, csr, e);

  k_gemm<false><<<gG, 256, 0, stream>>>(x, W1, Ah, n, nullptr, nullptr, nullptr);
  k_agg<true><<<gAgg, 256, 0, stream>>>(Ah, B, off, bsums, csr, dinv, b1, st, n, e);
  k_gemm<true><<<gG, 256, 0, stream>>>(B, W2, Ah, n, st, gamma, beta);
  k_agg<false><<<gAgg, 256, 0, stream>>>(Ah, out, off, bsums, csr, dinv, b2, nullptr, n, e);
}